// Round 2
// baseline (160.541 us; speedup 1.0000x reference)
//
#include <hip/hip_runtime.h>
#include <hip/hip_bf16.h>
#include <math.h>

// Problem constants (from reference setup_inputs)
#define BB   8
#define N1   2048
#define N2   2048
#define KK   128
#define TH_  0.1f
#define SL1B 0.1f
#define EPS_ 1e-8f

// minsq workspace layout (uint32 bit-patterns of non-negative floats):
//  seg0 [0,      16384) : pts -> nearest kpt      (B*N1)  weight 0.5/16384
//  seg1 [16384,  17408) : kpt -> nearest pts      (B*K)   weight 0.5/1024
//  seg2 [17408,  33792) : pts -> nearest recon    (B*N1)  weight 0.5/16384
//  seg3 [33792,  50176) : recon -> nearest pts    (B*N2)  weight 0.5/16384
#define WS_TOTAL 50176

__device__ __forceinline__ void block_sum_atomic(float v, float* out) {
    __shared__ float sbuf[4];
    #pragma unroll
    for (int off = 32; off > 0; off >>= 1)
        v += __shfl_down(v, off, 64);
    if ((threadIdx.x & 63) == 0) sbuf[threadIdx.x >> 6] = v;
    __syncthreads();
    if (threadIdx.x == 0) {
        float s = sbuf[0] + sbuf[1] + sbuf[2] + sbuf[3];
        atomicAdd(out, s);
    }
}

// Each block: (batch=blockIdx.z, A-rows = blockIdx.x*256.., B-chunk = blockIdx.y)
// Stages CHUNK B-points in LDS (float4-padded, broadcast reads), computes
// per-A-row min squared distance over the chunk, atomicMin into ws.
template<int CHUNK>
__global__ void chamfer_min_chunk(const float* __restrict__ A,
                                  const float* __restrict__ Bset,
                                  unsigned int* __restrict__ minsq,
                                  int NA, int NB) {
    __shared__ float4 tile[CHUNK];
    const int b = blockIdx.z;
    const int i = blockIdx.x * 256 + threadIdx.x;
    const int cbase = blockIdx.y * CHUNK;

    for (int t = threadIdx.x; t < CHUNK; t += 256) {
        const float* p = Bset + ((size_t)b * NB + cbase + t) * 3;
        tile[t] = make_float4(p[0], p[1], p[2], 0.f);
    }
    __syncthreads();

    if (i < NA) {
        const float* pa = A + ((size_t)b * NA + i) * 3;
        const float ax = pa[0], ay = pa[1], az = pa[2];
        float m = 3.4e38f;
        #pragma unroll 8
        for (int t = 0; t < CHUNK; ++t) {
            float4 q = tile[t];
            float dx = ax - q.x, dy = ay - q.y, dz = az - q.z;
            float d2 = dx * dx + dy * dy + dz * dz;
            m = fminf(m, d2);
        }
        atomicMin(&minsq[(size_t)b * NA + i], __float_as_uint(m));
    }
}

__global__ void finalize_kernel(const unsigned int* __restrict__ minsq,
                                float* __restrict__ out) {
    const int g = blockIdx.x * 256 + threadIdx.x;   // grid covers exactly WS_TOTAL
    float d2 = __uint_as_float(minsq[g]);
    float w = (g >= 16384 && g < 17408) ? (0.5f / 1024.0f) : (0.5f / 16384.0f);
    float v = sqrtf(d2) * w;
    block_sum_atomic(v, out);
}

// blocks [0,512): diversity; [512,576): delta; [576,580): nocs; 580: pose
__global__ void small_terms_kernel(const float* __restrict__ kpt,
                                   const float* __restrict__ rdelta,
                                   const float* __restrict__ pnocs,
                                   const float* __restrict__ prot,
                                   const float* __restrict__ ptr_,
                                   const float* __restrict__ psz,
                                   const float* __restrict__ rl,
                                   const float* __restrict__ tl,
                                   const float* __restrict__ sl,
                                   float* __restrict__ out) {
    const int blk = blockIdx.x;
    float v = 0.f;
    if (blk < 512) {
        // diversity: g in [0, B*K*K)
        const int g = blk * 256 + threadIdx.x;
        const int b = g >> 14, i = (g >> 7) & 127, j = g & 127;
        const float* pi = kpt + ((size_t)((b << 7) + i)) * 3;
        const float* pj = kpt + ((size_t)((b << 7) + j)) * 3;
        float dx = pi[0] - pj[0], dy = pi[1] - pj[1], dz = pi[2] - pj[2];
        float d2 = dx * dx + dy * dy + dz * dz;
        float d = (i == j) ? TH_ : fminf(sqrtf(d2), TH_);
        v = d * (1.0f / 131072.0f);
    } else if (blk < 576) {
        // delta magnitude: g in [0, B*N2)
        const int g = (blk - 512) * 256 + threadIdx.x;
        const float* p = rdelta + (size_t)g * 3;
        v = sqrtf(p[0] * p[0] + p[1] * p[1] + p[2] * p[2]) * (1.0f / 16384.0f);
    } else if (blk < 580) {
        // NOCS smooth-L1: g in [0, B*K)
        const int g = (blk - 576) * 256 + threadIdx.x;
        const int b = g >> 7, k = g & 127;
        const float* s3 = sl + b * 3;
        float scale = sqrtf(s3[0] * s3[0] + s3[1] * s3[1] + s3[2] * s3[2]) + EPS_;
        const float* t3 = tl + b * 3;
        const float* p3 = kpt + ((size_t)((b << 7) + k)) * 3;
        float p0 = (p3[0] - t3[0]) / scale;
        float p1 = (p3[1] - t3[1]) / scale;
        float p2 = (p3[2] - t3[2]) / scale;
        const float* R = rl + b * 9;
        const float* pn = pnocs + ((size_t)((b << 7) + k)) * 3;
        float s = 0.f;
        #pragma unroll
        for (int j = 0; j < 3; ++j) {
            float gt = p0 * R[j] + p1 * R[3 + j] + p2 * R[6 + j];
            float diff = fabsf(pn[j] - gt);
            s += (diff > SL1B) ? (diff - 0.5f * SL1B) : (diff * diff * (0.5f / SL1B));
        }
        v = s * (1.0f / 1024.0f);
    } else {
        // pose: 8 threads, one batch each
        if (threadIdx.x < BB) {
            const int b = threadIdx.x;
            float s = 0.f;
            #pragma unroll
            for (int j = 0; j < 3; ++j) {
                float c = 0.f;
                #pragma unroll
                for (int i = 0; i < 3; ++i) {
                    float d = prot[b * 9 + i * 3 + j] - rl[b * 9 + i * 3 + j];
                    c += d * d;
                }
                s += sqrtf(c);
            }
            v = s * (1.0f / 24.0f);
            float dt2 = 0.f, ds2 = 0.f;
            #pragma unroll
            for (int i = 0; i < 3; ++i) {
                float dt = ptr_[b * 3 + i] - tl[b * 3 + i]; dt2 += dt * dt;
                float ds = psz[b * 3 + i] - sl[b * 3 + i]; ds2 += ds * ds;
            }
            v += (sqrtf(dt2) + sqrtf(ds2)) * (1.0f / 8.0f);
        }
    }
    block_sum_atomic(v, out);
}

extern "C" void kernel_launch(void* const* d_in, const int* in_sizes, int n_in,
                              void* d_out, int out_size, void* d_ws, size_t ws_size,
                              hipStream_t stream) {
    const float* pts    = (const float*)d_in[0];
    const float* rdelta = (const float*)d_in[1];
    const float* kpt    = (const float*)d_in[2];
    const float* recon  = (const float*)d_in[3];
    const float* pnocs  = (const float*)d_in[4];
    const float* prot   = (const float*)d_in[5];
    const float* ptr_   = (const float*)d_in[6];
    const float* psz    = (const float*)d_in[7];
    const float* rl     = (const float*)d_in[8];
    const float* tl     = (const float*)d_in[9];
    const float* sl     = (const float*)d_in[10];
    float* out = (float*)d_out;
    unsigned int* ws = (unsigned int*)d_ws;

    // d_out/d_ws are poisoned 0xAA before every call — init here (stream ops, capturable)
    hipMemsetAsync(d_out, 0, sizeof(float), stream);
    hipMemsetAsync(d_ws, 0xFF, WS_TOTAL * sizeof(unsigned int), stream);

    small_terms_kernel<<<581, 256, 0, stream>>>(kpt, rdelta, pnocs, prot, ptr_, psz,
                                                rl, tl, sl, out);

    // pts -> kpt (min over K per pts point)
    chamfer_min_chunk<128><<<dim3(N1 / 256, 1, BB), 256, 0, stream>>>(
        pts, kpt, ws + 0, N1, KK);
    // kpt -> pts (min over N1 per kpt)
    chamfer_min_chunk<256><<<dim3(1, N1 / 256, BB), 256, 0, stream>>>(
        kpt, pts, ws + 16384, KK, N1);
    // pts -> recon (min over N2 per pts point)
    chamfer_min_chunk<256><<<dim3(N1 / 256, N2 / 256, BB), 256, 0, stream>>>(
        pts, recon, ws + 17408, N1, N2);
    // recon -> pts (min over N1 per recon point)
    chamfer_min_chunk<256><<<dim3(N2 / 256, N1 / 256, BB), 256, 0, stream>>>(
        recon, pts, ws + 33792, N2, N1);

    finalize_kernel<<<WS_TOTAL / 256, 256, 0, stream>>>(ws, out);
}

// Round 5
// 125.270 us; speedup vs baseline: 1.2816x; 1.2816x over previous
//
#include <hip/hip_runtime.h>
#include <hip/hip_bf16.h>
#include <math.h>

// Problem constants (from reference setup_inputs)
#define BB   8
#define N1   2048
#define N2   2048
#define KK   128
#define TH_  0.1f
#define SL1B 0.1f
#define EPS_ 1e-8f

// Single fused kernel, block-specialized:
//  [0,   256) : pts  -> recon  chamfer   (b=blk>>5, 64 rows/blk, 4-way scan split)
//  [256, 512) : recon-> pts    chamfer
//  [512, 528) : kpt  -> pts    chamfer   (b=l>>1, 64 rows/blk)
//  [528, 592) : pts  -> kpt    chamfer   (b=l>>3, 256 rows/blk, 1-way, scan=128)
//  [592, 656) : diversity (64 blks x 256 thr x 8 pairs)
//  [656, 720) : delta norm (64 blks x 256 thr x 1 pt)
//  [720, 724) : NOCS smooth-L1 (4 blks x 256)
//  [724]      : pose
#define NBLOCKS 725

__global__ __launch_bounds__(256) void loss_mega_kernel(
        const float* __restrict__ pts,
        const float* __restrict__ rdelta,
        const float* __restrict__ kpt,
        const float* __restrict__ recon,
        const float* __restrict__ pnocs,
        const float* __restrict__ prot,
        const float* __restrict__ ptr_,
        const float* __restrict__ psz,
        const float* __restrict__ rl,
        const float* __restrict__ tl,
        const float* __restrict__ sl,
        float* __restrict__ out) {
    __shared__ float4 tile[2048];   // staged B-set (x,y,z,pad)
    __shared__ float  part[256];    // split-combine buffer
    __shared__ float  sbuf[4];      // per-wave sums

    const int blk = blockIdx.x;
    const int t   = threadIdx.x;
    float v = 0.f;

    if (blk < 592) {
        // ---- generic complete-row chamfer ----
        const float *Ap, *Bp;
        int NA, NB, rowsLog, rowbase, b;
        float w;
        if (blk < 256) {
            b = blk >> 5; Ap = pts;  NA = N1; Bp = recon; NB = N2;
            rowsLog = 6; rowbase = (blk & 31) << 6; w = 0.5f / 16384.f;
        } else if (blk < 512) {
            int l = blk - 256;
            b = l >> 5; Ap = recon; NA = N2; Bp = pts; NB = N1;
            rowsLog = 6; rowbase = (l & 31) << 6; w = 0.5f / 16384.f;
        } else if (blk < 528) {
            int l = blk - 512;
            b = l >> 1; Ap = kpt; NA = KK; Bp = pts; NB = N1;
            rowsLog = 6; rowbase = (l & 1) << 6; w = 0.5f / 1024.f;
        } else {
            int l = blk - 528;
            b = l >> 3; Ap = pts; NA = N1; Bp = kpt; NB = KK;
            rowsLog = 8; rowbase = (l & 7) << 8; w = 0.5f / 16384.f;
        }
        const int rows  = 1 << rowsLog;       // 64 or 256
        const int split = 256 >> rowsLog;     // 4 or 1
        const int scan  = NB / split;         // 512, or 128

        // stage all NB points of batch b into LDS
        for (int j = t; j < NB; j += 256) {
            const float* p = Bp + ((size_t)b * NB + j) * 3;
            tile[j] = make_float4(p[0], p[1], p[2], 0.f);
        }
        __syncthreads();

        const int rlocal = t & (rows - 1);
        const int q      = t >> rowsLog;
        const int row    = rowbase + rlocal;
        const float* pa  = Ap + ((size_t)b * NA + row) * 3;
        const float ax = pa[0], ay = pa[1], az = pa[2];

        float m = 3.4e38f;
        const int off = q * scan;
        #pragma unroll 8
        for (int j = 0; j < scan; ++j) {
            float4 qq = tile[off + j];          // wave-broadcast read
            float dx = ax - qq.x, dy = ay - qq.y, dz = az - qq.z;
            m = fminf(m, dx * dx + dy * dy + dz * dz);
        }
        part[t] = m;
        __syncthreads();
        if (t < rows) {
            #pragma unroll
            for (int s = 1; s < 4; ++s)
                if (s < split) m = fminf(m, part[t + (s << rowsLog)]);
            v = sqrtf(m) * w;
        }
    } else if (blk < 656) {
        // ---- diversity: 64 blocks x 256 thr x 8 pairs ----
        const int local = blk - 592;
        float acc = 0.f;
        #pragma unroll
        for (int u = 0; u < 8; ++u) {
            const int g = local * 2048 + u * 256 + t;    // [0, 131072)
            const int b = g >> 14, i = (g >> 7) & 127, j = g & 127;
            const float* pi = kpt + ((size_t)((b << 7) + i)) * 3;
            const float* pj = kpt + ((size_t)((b << 7) + j)) * 3;
            float dx = pi[0] - pj[0], dy = pi[1] - pj[1], dz = pi[2] - pj[2];
            float d2 = dx * dx + dy * dy + dz * dz;
            acc += (i == j) ? TH_ : fminf(sqrtf(d2), TH_);
        }
        v = acc * (1.0f / 131072.0f);
    } else if (blk < 720) {
        // ---- delta magnitude: 64 blocks x 256 thr x 1 point ----
        const int g = (blk - 656) * 256 + t;             // [0, 16384)
        const float* p = rdelta + (size_t)g * 3;
        v = sqrtf(p[0] * p[0] + p[1] * p[1] + p[2] * p[2]) * (1.0f / 16384.0f);
    } else if (blk < 724) {
        // ---- NOCS smooth-L1: 4 blocks x 256 thr ----
        const int g = (blk - 720) * 256 + t;             // [0, 1024)
        const int b = g >> 7, k = g & 127;
        const float* s3 = sl + b * 3;
        float scale = sqrtf(s3[0] * s3[0] + s3[1] * s3[1] + s3[2] * s3[2]) + EPS_;
        const float* t3 = tl + b * 3;
        const float* p3 = kpt + ((size_t)((b << 7) + k)) * 3;
        float p0 = (p3[0] - t3[0]) / scale;
        float p1 = (p3[1] - t3[1]) / scale;
        float p2 = (p3[2] - t3[2]) / scale;
        const float* R = rl + b * 9;
        const float* pn = pnocs + ((size_t)((b << 7) + k)) * 3;
        float s = 0.f;
        #pragma unroll
        for (int j = 0; j < 3; ++j) {
            float gt = p0 * R[j] + p1 * R[3 + j] + p2 * R[6 + j];
            float diff = fabsf(pn[j] - gt);
            s += (diff > SL1B) ? (diff - 0.5f * SL1B) : (diff * diff * (0.5f / SL1B));
        }
        v = s * (1.0f / 1024.0f);
    } else {
        // ---- pose: one block, 8 active threads ----
        if (t < BB) {
            const int b = t;
            float s = 0.f;
            #pragma unroll
            for (int j = 0; j < 3; ++j) {
                float c = 0.f;
                #pragma unroll
                for (int i = 0; i < 3; ++i) {
                    float d = prot[b * 9 + i * 3 + j] - rl[b * 9 + i * 3 + j];
                    c += d * d;
                }
                s += sqrtf(c);
            }
            v = s * (1.0f / 24.0f);
            float dt2 = 0.f, ds2 = 0.f;
            #pragma unroll
            for (int i = 0; i < 3; ++i) {
                float dt = ptr_[b * 3 + i] - tl[b * 3 + i]; dt2 += dt * dt;
                float ds = psz[b * 3 + i] - sl[b * 3 + i]; ds2 += ds * ds;
            }
            v += (sqrtf(dt2) + sqrtf(ds2)) * (1.0f / 8.0f);
        }
    }

    // block reduction + single atomicAdd (uniform control flow per block)
    #pragma unroll
    for (int off = 32; off > 0; off >>= 1)
        v += __shfl_down(v, off, 64);
    if ((t & 63) == 0) sbuf[t >> 6] = v;
    __syncthreads();
    if (t == 0) atomicAdd(out, sbuf[0] + sbuf[1] + sbuf[2] + sbuf[3]);
}

extern "C" void kernel_launch(void* const* d_in, const int* in_sizes, int n_in,
                              void* d_out, int out_size, void* d_ws, size_t ws_size,
                              hipStream_t stream) {
    const float* pts    = (const float*)d_in[0];
    const float* rdelta = (const float*)d_in[1];
    const float* kpt    = (const float*)d_in[2];
    const float* recon  = (const float*)d_in[3];
    const float* pnocs  = (const float*)d_in[4];
    const float* prot   = (const float*)d_in[5];
    const float* ptr_   = (const float*)d_in[6];
    const float* psz    = (const float*)d_in[7];
    const float* rl     = (const float*)d_in[8];
    const float* tl     = (const float*)d_in[9];
    const float* sl     = (const float*)d_in[10];
    float* out = (float*)d_out;

    // d_out poisoned 0xAA before every call — zero it (stream op, capturable)
    hipMemsetAsync(d_out, 0, sizeof(float), stream);

    loss_mega_kernel<<<NBLOCKS, 256, 0, stream>>>(
        pts, rdelta, kpt, recon, pnocs, prot, ptr_, psz, rl, tl, sl, out);
}

// Round 7
// 90.829 us; speedup vs baseline: 1.7675x; 1.3792x over previous
//
#include <hip/hip_runtime.h>
#include <hip/hip_bf16.h>
#include <math.h>

// Problem constants (from reference setup_inputs)
#define BB   8
#define N1   2048
#define N2   2048
#define KK   128
#define TH_  0.1f
#define SL1B 0.1f
#define EPS_ 1e-8f

// Block map (413 blocks, 256 threads each):
//  [0,  128) : pts  -> recon  chamfer  (split path: 128 rows/blk, R=4, SPLIT=8)
//  [128,256) : recon-> pts    chamfer  (split path)
//  [256,264) : kpt  -> pts    chamfer  (split path, 1 blk/batch)
//  [264,280) : pts  -> kpt    chamfer  (full path: 1024 rows/blk, R=4, SPLIT=1)
//  [280,344) : diversity (64 blks x 256 thr x 8 pairs)
//  [344,408) : delta norm (64 blks x 256 thr x 1 pt)
//  [408,412) : NOCS smooth-L1 (4 blks x 256)
//  [412]     : pose
#define NBLOCKS 413

// Chamfer trick: d2(a,b) = |a|^2 + (|b|^2 - 2 a.b). Stage (-2bx,-2by,-2bz,|b|^2)
// in LDS; per pair only 3 fma + 1 min; fold |a|^2 after the min (shift-invariant),
// clamp at 0 before sqrt (expansion cancellation guard).

__global__ __launch_bounds__(256) void loss_mega_kernel(
        const float* __restrict__ pts,
        const float* __restrict__ rdelta,
        const float* __restrict__ kpt,
        const float* __restrict__ recon,
        const float* __restrict__ pnocs,
        const float* __restrict__ prot,
        const float* __restrict__ ptr_,
        const float* __restrict__ psz,
        const float* __restrict__ rl,
        const float* __restrict__ tl,
        const float* __restrict__ sl,
        float* __restrict__ out) {
    __shared__ float4 tile[2048];    // (-2bx,-2by,-2bz,|b|^2)      32 KB
    __shared__ float  part[1024];    // [split=8][rows=128] partial mins  4 KB
    __shared__ float  sbuf[4];

    const int blk = blockIdx.x;
    const int t   = threadIdx.x;
    float v = 0.f;

    if (blk < 264) {
        // ---------- split-path chamfer: 128 rows/blk, R=4, SPLIT=8, SCAN=NB/8 ----------
        const float *Ap, *Bp;
        int NA, NB, rowbase, b;
        float w;
        if (blk < 128) {
            b = blk >> 4; Ap = pts;  NA = N1; Bp = recon; NB = N2;
            rowbase = (blk & 15) << 7; w = 0.5f / 16384.f;
        } else if (blk < 256) {
            int l = blk - 128;
            b = l >> 4; Ap = recon; NA = N2; Bp = pts; NB = N1;
            rowbase = (l & 15) << 7; w = 0.5f / 16384.f;
        } else {
            b = blk - 256; Ap = kpt; NA = KK; Bp = pts; NB = N1;
            rowbase = 0; w = 0.5f / 1024.f;
        }
        const int scan = NB >> 3;                 // 256

        // stage all NB points of batch b, transformed
        for (int j = t; j < NB; j += 256) {
            const float* p = Bp + ((size_t)b * NB + j) * 3;
            float x = p[0], y = p[1], z = p[2];
            tile[j] = make_float4(-2.f * x, -2.f * y, -2.f * z,
                                  x * x + y * y + z * z);
        }
        __syncthreads();

        const int rid = t & 31;                   // row-group (4 rows each)
        const int q   = t >> 5;                   // split index 0..7
        float ax[4], ay[4], az[4], asq[4], m[4];
        #pragma unroll
        for (int k = 0; k < 4; ++k) {
            const float* pa = Ap + ((size_t)b * NA + rowbase + rid * 4 + k) * 3;
            ax[k] = pa[0]; ay[k] = pa[1]; az[k] = pa[2];
            asq[k] = ax[k] * ax[k] + ay[k] * ay[k] + az[k] * az[k];
            m[k] = 3.4e38f;
        }

        const int off = q * scan;
        #pragma unroll 4
        for (int j = 0; j < scan; ++j) {
            float4 qv = tile[off + j];            // 2 addrs/wave: free 2-way
            #pragma unroll
            for (int k = 0; k < 4; ++k) {
                float e = fmaf(ax[k], qv.x,
                          fmaf(ay[k], qv.y,
                          fmaf(az[k], qv.z, qv.w)));
                m[k] = fminf(m[k], e);
            }
        }
        #pragma unroll
        for (int k = 0; k < 4; ++k)
            part[q * 128 + rid * 4 + k] = asq[k] + m[k];
        __syncthreads();
        if (t < 128) {
            float mm = part[t];
            #pragma unroll
            for (int qq = 1; qq < 8; ++qq)
                mm = fminf(mm, part[qq * 128 + t]);
            v = sqrtf(fmaxf(mm, 0.f)) * w;
        }
    } else if (blk < 280) {
        // ---------- full-path chamfer: pts -> kpt, 1024 rows/blk, R=4, SPLIT=1 ----------
        const int l = blk - 264;
        const int b = l >> 1;
        const int rowbase = (l & 1) << 10;
        const float w = 0.5f / 16384.f;

        for (int j = t; j < KK; j += 256) {
            const float* p = kpt + ((size_t)b * KK + j) * 3;
            float x = p[0], y = p[1], z = p[2];
            tile[j] = make_float4(-2.f * x, -2.f * y, -2.f * z,
                                  x * x + y * y + z * z);
        }
        __syncthreads();

        float ax[4], ay[4], az[4], asq[4], m[4];
        #pragma unroll
        for (int k = 0; k < 4; ++k) {
            const float* pa = pts + ((size_t)b * N1 + rowbase + t * 4 + k) * 3;
            ax[k] = pa[0]; ay[k] = pa[1]; az[k] = pa[2];
            asq[k] = ax[k] * ax[k] + ay[k] * ay[k] + az[k] * az[k];
            m[k] = 3.4e38f;
        }
        #pragma unroll 4
        for (int j = 0; j < KK; ++j) {
            float4 qv = tile[j];                  // pure broadcast
            #pragma unroll
            for (int k = 0; k < 4; ++k) {
                float e = fmaf(ax[k], qv.x,
                          fmaf(ay[k], qv.y,
                          fmaf(az[k], qv.z, qv.w)));
                m[k] = fminf(m[k], e);
            }
        }
        float s = 0.f;
        #pragma unroll
        for (int k = 0; k < 4; ++k)
            s += sqrtf(fmaxf(asq[k] + m[k], 0.f));
        v = s * w;
    } else if (blk < 344) {
        // ---------- diversity: 64 blocks x 256 thr x 8 pairs ----------
        const int local = blk - 280;
        float acc = 0.f;
        #pragma unroll
        for (int u = 0; u < 8; ++u) {
            const int g = local * 2048 + u * 256 + t;    // [0, 131072)
            const int b = g >> 14, i = (g >> 7) & 127, j = g & 127;
            const float* pi = kpt + ((size_t)((b << 7) + i)) * 3;
            const float* pj = kpt + ((size_t)((b << 7) + j)) * 3;
            float dx = pi[0] - pj[0], dy = pi[1] - pj[1], dz = pi[2] - pj[2];
            float d2 = dx * dx + dy * dy + dz * dz;
            acc += (i == j) ? TH_ : fminf(sqrtf(d2), TH_);
        }
        v = acc * (1.0f / 131072.0f);
    } else if (blk < 408) {
        // ---------- delta magnitude ----------
        const int g = (blk - 344) * 256 + t;             // [0, 16384)
        const float* p = rdelta + (size_t)g * 3;
        v = sqrtf(p[0] * p[0] + p[1] * p[1] + p[2] * p[2]) * (1.0f / 16384.0f);
    } else if (blk < 412) {
        // ---------- NOCS smooth-L1 ----------
        const int g = (blk - 408) * 256 + t;             // [0, 1024)
        const int b = g >> 7, k = g & 127;
        const float* s3 = sl + b * 3;
        float scale = sqrtf(s3[0] * s3[0] + s3[1] * s3[1] + s3[2] * s3[2]) + EPS_;
        const float* t3 = tl + b * 3;
        const float* p3 = kpt + ((size_t)((b << 7) + k)) * 3;
        float p0 = (p3[0] - t3[0]) / scale;
        float p1 = (p3[1] - t3[1]) / scale;
        float p2 = (p3[2] - t3[2]) / scale;
        const float* R = rl + b * 9;
        const float* pn = pnocs + ((size_t)((b << 7) + k)) * 3;
        float s = 0.f;
        #pragma unroll
        for (int j = 0; j < 3; ++j) {
            float gt = p0 * R[j] + p1 * R[3 + j] + p2 * R[6 + j];
            float diff = fabsf(pn[j] - gt);
            s += (diff > SL1B) ? (diff - 0.5f * SL1B) : (diff * diff * (0.5f / SL1B));
        }
        v = s * (1.0f / 1024.0f);
    } else {
        // ---------- pose ----------
        if (t < BB) {
            const int b = t;
            float s = 0.f;
            #pragma unroll
            for (int j = 0; j < 3; ++j) {
                float c = 0.f;
                #pragma unroll
                for (int i = 0; i < 3; ++i) {
                    float d = prot[b * 9 + i * 3 + j] - rl[b * 9 + i * 3 + j];
                    c += d * d;
                }
                s += sqrtf(c);
            }
            v = s * (1.0f / 24.0f);
            float dt2 = 0.f, ds2 = 0.f;
            #pragma unroll
            for (int i = 0; i < 3; ++i) {
                float dt = ptr_[b * 3 + i] - tl[b * 3 + i]; dt2 += dt * dt;
                float ds = psz[b * 3 + i] - sl[b * 3 + i]; ds2 += ds * ds;
            }
            v += (sqrtf(dt2) + sqrtf(ds2)) * (1.0f / 8.0f);
        }
    }

    // block reduction + single atomicAdd (uniform control flow per block)
    #pragma unroll
    for (int off = 32; off > 0; off >>= 1)
        v += __shfl_down(v, off, 64);
    if ((t & 63) == 0) sbuf[t >> 6] = v;
    __syncthreads();
    if (t == 0) atomicAdd(out, sbuf[0] + sbuf[1] + sbuf[2] + sbuf[3]);
}

extern "C" void kernel_launch(void* const* d_in, const int* in_sizes, int n_in,
                              void* d_out, int out_size, void* d_ws, size_t ws_size,
                              hipStream_t stream) {
    const float* pts    = (const float*)d_in[0];
    const float* rdelta = (const float*)d_in[1];
    const float* kpt    = (const float*)d_in[2];
    const float* recon  = (const float*)d_in[3];
    const float* pnocs  = (const float*)d_in[4];
    const float* prot   = (const float*)d_in[5];
    const float* ptr_   = (const float*)d_in[6];
    const float* psz    = (const float*)d_in[7];
    const float* rl     = (const float*)d_in[8];
    const float* tl     = (const float*)d_in[9];
    const float* sl     = (const float*)d_in[10];
    float* out = (float*)d_out;

    // d_out poisoned 0xAA before every call — zero it (stream op, capturable)
    hipMemsetAsync(d_out, 0, sizeof(float), stream);

    loss_mega_kernel<<<NBLOCKS, 256, 0, stream>>>(
        pts, rdelta, kpt, recon, pnocs, prot, ptr_, psz, rl, tl, sl, out);
}

// Round 9
// 87.631 us; speedup vs baseline: 1.8320x; 1.0365x over previous
//
#include <hip/hip_runtime.h>
#include <hip/hip_bf16.h>
#include <math.h>

// Problem constants (from reference setup_inputs)
#define BB   8
#define N1   2048
#define N2   2048
#define KK   128
#define TH_  0.1f
#define SL1B 0.1f
#define EPS_ 1e-8f

// Block map (677 blocks, 256 threads each). Chamfer "units" are uniform
// 64-row x 2048-scan blocks (SPLIT=16, SCAN=128, R=4 rows/thread):
//  [0,  256) : pts  -> recon   (b=blk>>5, rowbase=(blk&31)<<6)
//  [256,512) : recon-> pts
//  [512,528) : kpt  -> pts     (b=l>>1, rowbase=(l&1)<<6)
//  [528,544) : pts  -> kpt     full path: 1024 rows/blk, scan=128 broadcast
//  [544,608) : diversity (64 blks x 256 thr x 8 pairs)
//  [608,672) : delta norm (64 blks)
//  [672,676) : NOCS smooth-L1 (4 blks)
//  [676]     : pose
#define NBLOCKS 677

// Chamfer trick: d2(a,b) = |a|^2 + (|b|^2 - 2 a.b). Stage (-2bx,-2by,-2bz,|b|^2)
// in LDS; per pair 3 fma + 1 min; fold |a|^2 after the min (shift-invariant),
// clamp at 0 before sqrt (expansion cancellation guard).
// Tile stride 129 (pad +1 per 128-chunk): the 4 split-addresses per wave land
// 516 dwords apart = 4 banks apart -> ds_read_b128 conflict-free.

#define SCAN  128
#define TS    129   // padded tile stride
#define SPLIT 16
#define ROWS  64

__global__ __launch_bounds__(256) void loss_mega_kernel(
        const float* __restrict__ pts,
        const float* __restrict__ rdelta,
        const float* __restrict__ kpt,
        const float* __restrict__ recon,
        const float* __restrict__ pnocs,
        const float* __restrict__ prot,
        const float* __restrict__ ptr_,
        const float* __restrict__ psz,
        const float* __restrict__ rl,
        const float* __restrict__ tl,
        const float* __restrict__ sl,
        float* __restrict__ out) {
    __shared__ float4 tile[SPLIT * TS];   // 2064 f4 = 33 KB
    __shared__ float  part[SPLIT * ROWS]; // 1024 f  = 4 KB
    __shared__ float  sbuf[4];

    const int blk = blockIdx.x;
    const int t   = threadIdx.x;
    float v = 0.f;

    if (blk < 528) {
        // ---------- split-path chamfer: 64 rows/blk, R=4, SPLIT=16, SCAN=128 ----------
        const float *Ap, *Bp;
        int NA, rowbase, b;
        float w;
        if (blk < 256) {
            b = blk >> 5; Ap = pts;  NA = N1; Bp = recon;
            rowbase = (blk & 31) << 6; w = 0.5f / 16384.f;
        } else if (blk < 512) {
            int l = blk - 256;
            b = l >> 5; Ap = recon; NA = N2; Bp = pts;
            rowbase = (l & 31) << 6; w = 0.5f / 16384.f;
        } else {
            int l = blk - 512;
            b = l >> 1; Ap = kpt; NA = KK; Bp = pts;
            rowbase = (l & 1) << 6; w = 0.5f / 1024.f;
        }
        const int NB = 2048;

        // stage all NB points of batch b, transformed, padded layout
        for (int j = t; j < NB; j += 256) {
            const float* p = Bp + ((size_t)b * NB + j) * 3;
            float x = p[0], y = p[1], z = p[2];
            tile[j + (j >> 7)] = make_float4(-2.f * x, -2.f * y, -2.f * z,
                                             x * x + y * y + z * z);
        }
        __syncthreads();

        const int g = t & 15;                 // row-group (4 rows each)
        const int q = t >> 4;                 // split index 0..15
        float ax[4], ay[4], az[4], asq[4], m[4];
        #pragma unroll
        for (int k = 0; k < 4; ++k) {
            const float* pa = Ap + ((size_t)b * NA + rowbase + g * 4 + k) * 3;
            ax[k] = pa[0]; ay[k] = pa[1]; az[k] = pa[2];
            asq[k] = ax[k] * ax[k] + ay[k] * ay[k] + az[k] * az[k];
            m[k] = 3.4e38f;
        }

        const int off = q * TS;
        #pragma unroll 4
        for (int j = 0; j < SCAN; ++j) {
            float4 qv = tile[off + j];        // 4 addrs/wave, 4 banks apart: free
            #pragma unroll
            for (int k = 0; k < 4; ++k) {
                float e = fmaf(ax[k], qv.x,
                          fmaf(ay[k], qv.y,
                          fmaf(az[k], qv.z, qv.w)));
                m[k] = fminf(m[k], e);
            }
        }
        #pragma unroll
        for (int k = 0; k < 4; ++k)
            part[q * ROWS + g * 4 + k] = asq[k] + m[k];
        __syncthreads();
        if (t < ROWS) {
            float mm = part[t];
            #pragma unroll
            for (int qq = 1; qq < SPLIT; ++qq)
                mm = fminf(mm, part[qq * ROWS + t]);
            v = sqrtf(fmaxf(mm, 0.f)) * w;
        }
    } else if (blk < 544) {
        // ---------- full-path chamfer: pts -> kpt, 1024 rows/blk, R=4, broadcast ----------
        const int l = blk - 528;
        const int b = l >> 1;
        const int rowbase = (l & 1) << 10;
        const float w = 0.5f / 16384.f;

        for (int j = t; j < KK; j += 256) {
            const float* p = kpt + ((size_t)b * KK + j) * 3;
            float x = p[0], y = p[1], z = p[2];
            tile[j] = make_float4(-2.f * x, -2.f * y, -2.f * z,
                                  x * x + y * y + z * z);
        }
        __syncthreads();

        float ax[4], ay[4], az[4], asq[4], m[4];
        #pragma unroll
        for (int k = 0; k < 4; ++k) {
            const float* pa = pts + ((size_t)b * N1 + rowbase + t * 4 + k) * 3;
            ax[k] = pa[0]; ay[k] = pa[1]; az[k] = pa[2];
            asq[k] = ax[k] * ax[k] + ay[k] * ay[k] + az[k] * az[k];
            m[k] = 3.4e38f;
        }
        #pragma unroll 4
        for (int j = 0; j < KK; ++j) {
            float4 qv = tile[j];              // pure broadcast
            #pragma unroll
            for (int k = 0; k < 4; ++k) {
                float e = fmaf(ax[k], qv.x,
                          fmaf(ay[k], qv.y,
                          fmaf(az[k], qv.z, qv.w)));
                m[k] = fminf(m[k], e);
            }
        }
        float s = 0.f;
        #pragma unroll
        for (int k = 0; k < 4; ++k)
            s += sqrtf(fmaxf(asq[k] + m[k], 0.f));
        v = s * w;
    } else if (blk < 608) {
        // ---------- diversity: 64 blocks x 256 thr x 8 pairs ----------
        const int local = blk - 544;
        float acc = 0.f;
        #pragma unroll
        for (int u = 0; u < 8; ++u) {
            const int gg = local * 2048 + u * 256 + t;   // [0, 131072)
            const int b = gg >> 14, i = (gg >> 7) & 127, j = gg & 127;
            const float* pi = kpt + ((size_t)((b << 7) + i)) * 3;
            const float* pj = kpt + ((size_t)((b << 7) + j)) * 3;
            float dx = pi[0] - pj[0], dy = pi[1] - pj[1], dz = pi[2] - pj[2];
            float d2 = dx * dx + dy * dy + dz * dz;
            acc += (i == j) ? TH_ : fminf(sqrtf(d2), TH_);
        }
        v = acc * (1.0f / 131072.0f);
    } else if (blk < 672) {
        // ---------- delta magnitude ----------
        const int gg = (blk - 608) * 256 + t;            // [0, 16384)
        const float* p = rdelta + (size_t)gg * 3;
        v = sqrtf(p[0] * p[0] + p[1] * p[1] + p[2] * p[2]) * (1.0f / 16384.0f);
    } else if (blk < 676) {
        // ---------- NOCS smooth-L1 ----------
        const int gg = (blk - 672) * 256 + t;            // [0, 1024)
        const int b = gg >> 7, k = gg & 127;
        const float* s3 = sl + b * 3;
        float scale = sqrtf(s3[0] * s3[0] + s3[1] * s3[1] + s3[2] * s3[2]) + EPS_;
        const float* t3 = tl + b * 3;
        const float* p3 = kpt + ((size_t)((b << 7) + k)) * 3;
        float p0 = (p3[0] - t3[0]) / scale;
        float p1 = (p3[1] - t3[1]) / scale;
        float p2 = (p3[2] - t3[2]) / scale;
        const float* R = rl + b * 9;
        const float* pn = pnocs + ((size_t)((b << 7) + k)) * 3;
        float s = 0.f;
        #pragma unroll
        for (int j = 0; j < 3; ++j) {
            float gt = p0 * R[j] + p1 * R[3 + j] + p2 * R[6 + j];
            float diff = fabsf(pn[j] - gt);
            s += (diff > SL1B) ? (diff - 0.5f * SL1B) : (diff * diff * (0.5f / SL1B));
        }
        v = s * (1.0f / 1024.0f);
    } else {
        // ---------- pose ----------
        if (t < BB) {
            const int b = t;
            float s = 0.f;
            #pragma unroll
            for (int j = 0; j < 3; ++j) {
                float c = 0.f;
                #pragma unroll
                for (int i = 0; i < 3; ++i) {
                    float d = prot[b * 9 + i * 3 + j] - rl[b * 9 + i * 3 + j];
                    c += d * d;
                }
                s += sqrtf(c);
            }
            v = s * (1.0f / 24.0f);
            float dt2 = 0.f, ds2 = 0.f;
            #pragma unroll
            for (int i = 0; i < 3; ++i) {
                float dt = ptr_[b * 3 + i] - tl[b * 3 + i]; dt2 += dt * dt;
                float ds = psz[b * 3 + i] - sl[b * 3 + i]; ds2 += ds * ds;
            }
            v += (sqrtf(dt2) + sqrtf(ds2)) * (1.0f / 8.0f);
        }
    }

    // block reduction + single atomicAdd (uniform control flow per block)
    #pragma unroll
    for (int off = 32; off > 0; off >>= 1)
        v += __shfl_down(v, off, 64);
    if ((t & 63) == 0) sbuf[t >> 6] = v;
    __syncthreads();
    if (t == 0) atomicAdd(out, sbuf[0] + sbuf[1] + sbuf[2] + sbuf[3]);
}

extern "C" void kernel_launch(void* const* d_in, const int* in_sizes, int n_in,
                              void* d_out, int out_size, void* d_ws, size_t ws_size,
                              hipStream_t stream) {
    const float* pts    = (const float*)d_in[0];
    const float* rdelta = (const float*)d_in[1];
    const float* kpt    = (const float*)d_in[2];
    const float* recon  = (const float*)d_in[3];
    const float* pnocs  = (const float*)d_in[4];
    const float* prot   = (const float*)d_in[5];
    const float* ptr_   = (const float*)d_in[6];
    const float* psz    = (const float*)d_in[7];
    const float* rl     = (const float*)d_in[8];
    const float* tl     = (const float*)d_in[9];
    const float* sl     = (const float*)d_in[10];
    float* out = (float*)d_out;

    // d_out poisoned 0xAA before every call — zero it (stream op, capturable)
    hipMemsetAsync(d_out, 0, sizeof(float), stream);

    loss_mega_kernel<<<NBLOCKS, 256, 0, stream>>>(
        pts, rdelta, kpt, recon, pnocs, prot, ptr_, psz, rl, tl, sl, out);
}